// Round 2
// baseline (741.793 us; speedup 1.0000x reference)
//
#include <hip/hip_runtime.h>
#include <math.h>

#define N_OBS_C  1000000
#define NDIM     8192
#define RANK_C   64

typedef __attribute__((ext_vector_type(8))) short bf16x8;
typedef __attribute__((ext_vector_type(4))) float f32x4;

// round-to-nearest-even f32 -> bf16 bits
__device__ __forceinline__ unsigned short f2bf(float f) {
  union { float f; unsigned int u; } x; x.f = f;
  unsigned int u = x.u;
  unsigned int r = (u + 0x7fffu + ((u >> 16) & 1u)) >> 16;
  return (unsigned short)r;
}

__device__ __forceinline__ bf16x8 cvt8(f32x4 lo, f32x4 hi) {
  bf16x8 r;
  r[0] = (short)f2bf(lo[0]); r[1] = (short)f2bf(lo[1]);
  r[2] = (short)f2bf(lo[2]); r[3] = (short)f2bf(lo[3]);
  r[4] = (short)f2bf(hi[0]); r[5] = (short)f2bf(hi[1]);
  r[6] = (short)f2bf(hi[2]); r[7] = (short)f2bf(hi[3]);
  return r;
}

// ---------------------------------------------------------------------------
// Prep:
//  blocks 0..127  : V col-slab -> Vt f32 (8192x64, for gathers + S_V epilogue)
//                   and Vb bf16 (straight copy of V, 64x8192 = (Vt)^T)
//  blocks 128..255: U row-slab -> Utb bf16 (U^T, 64x8192)
// ---------------------------------------------------------------------------
__global__ void prep_kernel(const float* __restrict__ V, const float* __restrict__ U,
                            float* __restrict__ Vt, unsigned short* __restrict__ Utb,
                            unsigned short* __restrict__ Vb) {
  int b = blockIdx.x, t = threadIdx.x;
  __shared__ float tile[64][65];
  if (b < 128) {
    int c0 = b * 64;
#pragma unroll
    for (int i = 0; i < 16; ++i) {
      int idx = i * 256 + t;
      int r = idx >> 6, c = idx & 63;
      float v = V[r * NDIM + c0 + c];            // coalesced along n
      tile[r][c] = v;
      Vb[r * NDIM + c0 + c] = f2bf(v);           // coalesced 2B stores
    }
    __syncthreads();
#pragma unroll
    for (int i = 0; i < 16; ++i) {
      int idx = i * 256 + t;
      int n = idx >> 6, r = idx & 63;
      Vt[(c0 + n) * RANK_C + r] = tile[r][n];    // coalesced along r
    }
  } else {
    int i0 = (b - 128) * 64;
#pragma unroll
    for (int i = 0; i < 16; ++i) {
      int idx = i * 256 + t;
      int ii = idx >> 6, r = idx & 63;
      tile[ii][r] = U[(i0 + ii) * RANK_C + r];   // coalesced along r
    }
    __syncthreads();
#pragma unroll
    for (int i = 0; i < 16; ++i) {
      int idx = i * 256 + t;
      int r = idx >> 6, ii = idx & 63;
      Utb[r * NDIM + i0 + ii] = f2bf(tile[ii][r]);  // coalesced along i
    }
  }
}

__device__ __forceinline__ void block_reduce_atomic(float v, float* out) {
#pragma unroll
  for (int off = 32; off > 0; off >>= 1) v += __shfl_down(v, off, 64);
  __shared__ float wsum[4];
  int w = threadIdx.x >> 6;
  if ((threadIdx.x & 63) == 0) wsum[w] = v;
  __syncthreads();
  if (threadIdx.x == 0) atomicAdd(out, wsum[0] + wsum[1] + wsum[2] + wsum[3]);
}

// ---------------------------------------------------------------------------
// Fused main kernel. bid % 5 == 0 -> energy gather block (256 of them).
// Else: one S-block = 128 rows x 1024 K-chunk of S_U (first 512) or S_V.
// W_part = S_chunk (bf16, cvt on the fly, A-operand, dwordx4 loads)
//          x factor^T row-chunks (bf16 B-operand); epilogue dots W_part
//          with the f32 factor and atomically accumulates.
// ---------------------------------------------------------------------------
__global__ void __launch_bounds__(256, 4)
main_kernel(const float* __restrict__ vals, const int* __restrict__ rows,
            const int* __restrict__ cols, const float* __restrict__ U,
            const float* __restrict__ sigma, const float* __restrict__ S_U,
            const float* __restrict__ S_V, const float* __restrict__ Vt,
            const unsigned short* __restrict__ Utb,
            const unsigned short* __restrict__ Vb, float* __restrict__ out) {
  const int E_BLOCKS = 256;
  int bid = blockIdx.x;
  int t = threadIdx.x;

  if (bid % 5 == 0) {
    // ---------------- energy term ----------------
    int eb = bid / 5;                       // 0..255
    float s2 = sigma[0] * sigma[0];
    float local = 0.f;
    int stride = E_BLOCKS * 256;
    for (int n = eb * 256 + t; n < N_OBS_C; n += stride) {
      int r = rows[n], c = cols[n];
      const f32x4* up = (const f32x4*)(U  + (size_t)r * RANK_C);
      const f32x4* vp = (const f32x4*)(Vt + (size_t)c * RANK_C);
      float d0 = 0.f, d1 = 0.f, d2 = 0.f, d3 = 0.f;
#pragma unroll
      for (int k = 0; k < 16; k += 4) {
        f32x4 a0 = up[k],     b0 = vp[k];
        f32x4 a1 = up[k + 1], b1 = vp[k + 1];
        f32x4 a2 = up[k + 2], b2 = vp[k + 2];
        f32x4 a3 = up[k + 3], b3 = vp[k + 3];
        d0 += a0[0]*b0[0] + a0[1]*b0[1] + a0[2]*b0[2] + a0[3]*b0[3];
        d1 += a1[0]*b1[0] + a1[1]*b1[1] + a1[2]*b1[2] + a1[3]*b1[3];
        d2 += a2[0]*b2[0] + a2[1]*b2[1] + a2[2]*b2[2] + a2[3]*b2[3];
        d3 += a3[0]*b3[0] + a3[1]*b3[1] + a3[2]*b3[2] + a3[3]*b3[3];
      }
      float e = vals[n] - ((d0 + d1) + (d2 + d3));
      local += e * e;
    }
    local *= 1.0f / (2.0f * s2);
    if (bid == 0 && t == 0) local += (float)N_OBS_C * logf(s2);
    block_reduce_atomic(local, out);
  } else {
    // ---------------- S quadratic-form block ----------------
    int sb = (bid / 5) * 4 + (bid % 5 - 1);   // 0..1023
    const float* S; const unsigned short* Bt; const float* Fac;
    if (sb < 512) { S = S_U; Bt = Utb; Fac = U; }
    else          { S = S_V; Bt = Vb;  Fac = Vt; sb -= 512; }
    int i0 = (sb >> 3) * 128;      // row-strip origin (8192/128 = 64 strips)
    int k0 = (sb & 7) * 1024;      // K-chunk origin  (8 chunks)

    int w = t >> 6, lane = t & 63, quad = lane >> 4, lcol = lane & 15;
    int row0 = i0 + w * 32;        // this wave's 32 S-rows

    // A-operand (S): lane reads S[row][k + quad*8 .. +7] as two dwordx4.
    const float* Sr0 = S + (size_t)(row0 + lcol) * NDIM + k0 + quad * 8;
    const float* Sr1 = Sr0 + (size_t)16 * NDIM;
    // B-operand (factor^T row-chunks): Bt[n][k + quad*8 .. +7], 16B.
    const unsigned short* Bp = Bt + (size_t)lcol * NDIM + k0 + quad * 8;

    f32x4 acc[2][4];
#pragma unroll
    for (int a = 0; a < 2; ++a)
#pragma unroll
      for (int bq = 0; bq < 4; ++bq) acc[a][bq] = (f32x4){0.f, 0.f, 0.f, 0.f};

#pragma unroll 2
    for (int ks = 0; ks < 32; ++ks) {
      int koff = ks * 32;
      f32x4 a0lo = *(const f32x4*)(Sr0 + koff);
      f32x4 a0hi = *(const f32x4*)(Sr0 + koff + 4);
      f32x4 a1lo = *(const f32x4*)(Sr1 + koff);
      f32x4 a1hi = *(const f32x4*)(Sr1 + koff + 4);
      bf16x8 b0 = *(const bf16x8*)(Bp + koff);
      bf16x8 b1 = *(const bf16x8*)(Bp + 16 * NDIM + koff);
      bf16x8 b2 = *(const bf16x8*)(Bp + 32 * NDIM + koff);
      bf16x8 b3 = *(const bf16x8*)(Bp + 48 * NDIM + koff);
      bf16x8 a0 = cvt8(a0lo, a0hi);
      bf16x8 a1 = cvt8(a1lo, a1hi);
      acc[0][0] = __builtin_amdgcn_mfma_f32_16x16x32_bf16(a0, b0, acc[0][0], 0, 0, 0);
      acc[0][1] = __builtin_amdgcn_mfma_f32_16x16x32_bf16(a0, b1, acc[0][1], 0, 0, 0);
      acc[0][2] = __builtin_amdgcn_mfma_f32_16x16x32_bf16(a0, b2, acc[0][2], 0, 0, 0);
      acc[0][3] = __builtin_amdgcn_mfma_f32_16x16x32_bf16(a0, b3, acc[0][3], 0, 0, 0);
      acc[1][0] = __builtin_amdgcn_mfma_f32_16x16x32_bf16(a1, b0, acc[1][0], 0, 0, 0);
      acc[1][1] = __builtin_amdgcn_mfma_f32_16x16x32_bf16(a1, b1, acc[1][1], 0, 0, 0);
      acc[1][2] = __builtin_amdgcn_mfma_f32_16x16x32_bf16(a1, b2, acc[1][2], 0, 0, 0);
      acc[1][3] = __builtin_amdgcn_mfma_f32_16x16x32_bf16(a1, b3, acc[1][3], 0, 0, 0);
    }

    // Epilogue: W_part (C layout: n = nt*16 + lcol, i = row0 + ti*16 + quad*4 + reg)
    // dotted with f32 factor rows.
    float p = 0.f;
#pragma unroll
    for (int ti = 0; ti < 2; ++ti) {
      int ib = row0 + ti * 16 + quad * 4;
#pragma unroll
      for (int nt = 0; nt < 4; ++nt) {
        const float* fp = Fac + (size_t)ib * RANK_C + nt * 16 + lcol;
        p += fp[0 * RANK_C] * acc[ti][nt][0] + fp[1 * RANK_C] * acc[ti][nt][1]
           + fp[2 * RANK_C] * acc[ti][nt][2] + fp[3 * RANK_C] * acc[ti][nt][3];
      }
    }
    block_reduce_atomic(0.5f * p, out);
  }
}

extern "C" void kernel_launch(void* const* d_in, const int* in_sizes, int n_in,
                              void* d_out, int out_size, void* d_ws, size_t ws_size,
                              hipStream_t stream) {
  const float* vals  = (const float*)d_in[0];
  const int*   rows  = (const int*)  d_in[1];
  const int*   cols  = (const int*)  d_in[2];
  const float* U     = (const float*)d_in[3];
  const float* V     = (const float*)d_in[4];
  const float* sigma = (const float*)d_in[5];
  const float* S_U   = (const float*)d_in[6];
  const float* S_V   = (const float*)d_in[7];
  float* out = (float*)d_out;

  char* ws = (char*)d_ws;
  float*          Vt  = (float*)ws;                                  // 2 MB
  unsigned short* Utb = (unsigned short*)(ws + 2u * 1024 * 1024);    // 1 MB
  unsigned short* Vb  = (unsigned short*)(ws + 3u * 1024 * 1024);    // 1 MB

  hipMemsetAsync(d_out, 0, sizeof(float), stream);
  prep_kernel<<<256, 256, 0, stream>>>(V, U, Vt, Utb, Vb);
  // 256 energy blocks interleaved 1-in-5 with 1024 S-blocks
  main_kernel<<<1280, 256, 0, stream>>>(vals, rows, cols, U, sigma, S_U, S_V,
                                        Vt, Utb, Vb, out);
}

// Round 3
// 589.360 us; speedup vs baseline: 1.2586x; 1.2586x over previous
//
#include <hip/hip_runtime.h>
#include <math.h>

#define N_OBS_C  1000000
#define NDIM     8192
#define RANK_C   64

typedef __attribute__((ext_vector_type(8))) short bf16x8;
typedef __attribute__((ext_vector_type(4))) float f32x4;

// round-to-nearest-even f32 -> bf16 bits
__device__ __forceinline__ unsigned short f2bf(float f) {
  union { float f; unsigned int u; } x; x.f = f;
  unsigned int u = x.u;
  unsigned int r = (u + 0x7fffu + ((u >> 16) & 1u)) >> 16;
  return (unsigned short)r;
}

// ---------------------------------------------------------------------------
// Prep (verified round 1): Vt[n][r] = V[r][n] (f32) + bf16 copies Ub, Vtb.
// ---------------------------------------------------------------------------
__global__ void prep_kernel(const float* __restrict__ V, const float* __restrict__ U,
                            float* __restrict__ Vt, unsigned short* __restrict__ Ub,
                            unsigned short* __restrict__ Vtb) {
  int b = blockIdx.x, t = threadIdx.x;
  if (b < 128) {
    __shared__ float tile[64][65];
    int c0 = b * 64;
#pragma unroll
    for (int i = 0; i < 16; ++i) {
      int idx = i * 256 + t;
      int r = idx >> 6, c = idx & 63;
      tile[r][c] = V[r * NDIM + c0 + c];
    }
    __syncthreads();
#pragma unroll
    for (int i = 0; i < 16; ++i) {
      int idx = i * 256 + t;
      int n = idx >> 6, r = idx & 63;
      float v = tile[r][n];
      Vt[(c0 + n) * RANK_C + r]  = v;
      Vtb[(c0 + n) * RANK_C + r] = f2bf(v);
    }
  } else {
    int nt  = 64 * 256;
    int tid = (b - 128) * 256 + t;
    for (int i = tid; i < NDIM * RANK_C; i += nt)
      Ub[i] = f2bf(U[i]);
  }
}

__device__ __forceinline__ void block_reduce_atomic(float v, float* out) {
#pragma unroll
  for (int off = 32; off > 0; off >>= 1) v += __shfl_down(v, off, 64);
  __shared__ float wsum[4];
  int w = threadIdx.x >> 6;
  if ((threadIdx.x & 63) == 0) wsum[w] = v;
  __syncthreads();
  if (threadIdx.x == 0) atomicAdd(out, wsum[0] + wsum[1] + wsum[2] + wsum[3]);
}

// ---------------------------------------------------------------------------
// Fused main kernel. bid % 5 == 0 -> energy gather block (2048 total).
// Else one 128x128 tile of S_U (first 4096) or S_V (next 4096):
//   G tile via bf16 MFMA -> LDS transpose to row-major Greg[16] (f32x4/lane)
//   -> S streamed with 16 INDEPENDENT dwordx4 loads/wave, FMA'd vs Greg.
// ---------------------------------------------------------------------------
__global__ void __launch_bounds__(256, 2)
main_kernel(const float* __restrict__ vals, const int* __restrict__ rows,
            const int* __restrict__ cols, const float* __restrict__ U,
            const float* __restrict__ sigma, const float* __restrict__ S_U,
            const float* __restrict__ S_V, const float* __restrict__ Vt,
            const unsigned short* __restrict__ Ub,
            const unsigned short* __restrict__ Vtb, float* __restrict__ out) {
  const int E_BLOCKS = 2048;
  const int TILES_PER = 64 * 64;
  int bid = blockIdx.x;
  int t = threadIdx.x;

  __shared__ float gbuf[4][16][132];   // per-wave 16x128 strip, pitch 132 (16B-aligned, 2-way banks)

  if (bid % 5 == 0) {
    // ---------------- energy term ----------------
    int eb = bid / 5;
    float s2 = sigma[0] * sigma[0];
    float local = 0.f;
    int stride = E_BLOCKS * 256;
    for (int n = eb * 256 + t; n < N_OBS_C; n += stride) {
      int r = rows[n], c = cols[n];
      const f32x4* up = (const f32x4*)(U  + (size_t)r * RANK_C);
      const f32x4* vp = (const f32x4*)(Vt + (size_t)c * RANK_C);
      float d0 = 0.f, d1 = 0.f, d2 = 0.f, d3 = 0.f;
#pragma unroll
      for (int k = 0; k < 16; k += 4) {
        f32x4 a0 = up[k],     b0 = vp[k];
        f32x4 a1 = up[k + 1], b1 = vp[k + 1];
        f32x4 a2 = up[k + 2], b2 = vp[k + 2];
        f32x4 a3 = up[k + 3], b3 = vp[k + 3];
        d0 += a0[0]*b0[0] + a0[1]*b0[1] + a0[2]*b0[2] + a0[3]*b0[3];
        d1 += a1[0]*b1[0] + a1[1]*b1[1] + a1[2]*b1[2] + a1[3]*b1[3];
        d2 += a2[0]*b2[0] + a2[1]*b2[1] + a2[2]*b2[2] + a2[3]*b2[3];
        d3 += a3[0]*b3[0] + a3[1]*b3[1] + a3[2]*b3[2] + a3[3]*b3[3];
      }
      float e = vals[n] - ((d0 + d1) + (d2 + d3));
      local += e * e;
    }
    local *= 1.0f / (2.0f * s2);
    if (bid == 0 && t == 0) local += (float)N_OBS_C * logf(s2);
    block_reduce_atomic(local, out);
  } else {
    // ---------------- S quadratic-form tile ----------------
    int sb = (bid / 5) * 4 + (bid % 5 - 1);   // 0..8191
    const float* S; const unsigned short* A;
    if (sb < TILES_PER) { S = S_U; A = Ub; }
    else                { S = S_V; A = Vtb; sb -= TILES_PER; }
    int ti0 = (sb >> 6) * 128;   // tile row origin
    int tj0 = (sb & 63) * 128;   // tile col origin

    int w = t >> 6, lane = t & 63, quad = lane >> 4, lcol = lane & 15;

    // A fragments: rows of this wave's 32-row strip
    bf16x8 af[2][2];
#pragma unroll
    for (int ti = 0; ti < 2; ++ti)
#pragma unroll
      for (int kh = 0; kh < 2; ++kh) {
        int row = ti0 + w * 32 + ti * 16 + lcol;
        af[ti][kh] = *(const bf16x8*)(A + (size_t)row * RANK_C + kh * 32 + quad * 8);
      }
    // B fragments: the tile's 128 columns (rows tj0..tj0+127 of A)
    bf16x8 bfr[8][2];
#pragma unroll
    for (int tj = 0; tj < 8; ++tj)
#pragma unroll
      for (int kh = 0; kh < 2; ++kh) {
        int row = tj0 + tj * 16 + lcol;
        bfr[tj][kh] = *(const bf16x8*)(A + (size_t)row * RANK_C + kh * 32 + quad * 8);
      }

    // G strip: rows [w*32, w*32+32) x 128 cols, C layout
    f32x4 acc[2][8];
#pragma unroll
    for (int ti = 0; ti < 2; ++ti)
#pragma unroll
      for (int tj = 0; tj < 8; ++tj) {
        f32x4 z = {0.f, 0.f, 0.f, 0.f};
        z = __builtin_amdgcn_mfma_f32_16x16x32_bf16(af[ti][0], bfr[tj][0], z, 0, 0, 0);
        z = __builtin_amdgcn_mfma_f32_16x16x32_bf16(af[ti][1], bfr[tj][1], z, 0, 0, 0);
        acc[ti][tj] = z;
      }

    // Transpose to row-major via per-wave LDS region, two 16-row halves.
    // Greg[i] = G[local row 2i+h][4*l31 .. +3], h=lane>>5, l31=lane&31.
    int h = lane >> 5, l31 = lane & 31;
    f32x4 Greg[16];
#pragma unroll
    for (int ti = 0; ti < 2; ++ti) {
#pragma unroll
      for (int tj = 0; tj < 8; ++tj)
#pragma unroll
        for (int reg = 0; reg < 4; ++reg)
          gbuf[w][quad * 4 + reg][tj * 16 + lcol] = acc[ti][tj][reg];
      __syncthreads();
#pragma unroll
      for (int i = 0; i < 8; ++i)
        Greg[ti * 8 + i] = *(const f32x4*)&gbuf[w][2 * i + h][4 * l31];
      __syncthreads();
    }

    // Stream S: 16 independent dwordx4 loads per wave, then FMA vs Greg.
    const float* Sp = S + (size_t)(ti0 + w * 32 + h) * NDIM + tj0 + 4 * l31;
    f32x4 sv[16];
#pragma unroll
    for (int i = 0; i < 16; ++i)
      sv[i] = *(const f32x4*)(Sp + (size_t)(2 * i) * NDIM);
    f32x4 sum = {0.f, 0.f, 0.f, 0.f};
#pragma unroll
    for (int i = 0; i < 16; ++i) sum += sv[i] * Greg[i];
    float p = (sum[0] + sum[1]) + (sum[2] + sum[3]);
    block_reduce_atomic(0.5f * p, out);
  }
}

extern "C" void kernel_launch(void* const* d_in, const int* in_sizes, int n_in,
                              void* d_out, int out_size, void* d_ws, size_t ws_size,
                              hipStream_t stream) {
  const float* vals  = (const float*)d_in[0];
  const int*   rows  = (const int*)  d_in[1];
  const int*   cols  = (const int*)  d_in[2];
  const float* U     = (const float*)d_in[3];
  const float* V     = (const float*)d_in[4];
  const float* sigma = (const float*)d_in[5];
  const float* S_U   = (const float*)d_in[6];
  const float* S_V   = (const float*)d_in[7];
  float* out = (float*)d_out;

  char* ws = (char*)d_ws;
  float*          Vt  = (float*)ws;                                  // 2 MB
  unsigned short* Ub  = (unsigned short*)(ws + 2u * 1024 * 1024);    // 1 MB
  unsigned short* Vtb = (unsigned short*)(ws + 3u * 1024 * 1024);    // 1 MB

  hipMemsetAsync(d_out, 0, sizeof(float), stream);
  prep_kernel<<<192, 256, 0, stream>>>(V, U, Vt, Ub, Vtb);
  // 2048 energy blocks interleaved 1-in-5 with 8192 S-tile blocks
  main_kernel<<<10240, 256, 0, stream>>>(vals, rows, cols, U, sigma, S_U, S_V,
                                         Vt, Ub, Vtb, out);
}